// Round 1
// baseline (650.940 us; speedup 1.0000x reference)
//
#include <hip/hip_runtime.h>
#include <cmath>

#define NB 4
#define NN 1024
#define ND 512
#define NH 8
#define KD 64
#define NDH 1024

#define NEG_INF (-__builtin_inff())

struct HeadConsts { float inv2s2[NH]; };

// ---------------- per-head QKV projection: Out[bh][n][k] = x[b,n,:] @ W[h][:,k] + bias[h][k]
__global__ __launch_bounds__(256) void qkv_kernel(
    const float* __restrict__ x,
    const float* __restrict__ qp, const float* __restrict__ kp, const float* __restrict__ vp,
    const float* __restrict__ qb, const float* __restrict__ kb, const float* __restrict__ vb,
    float* __restrict__ Qo, float* __restrict__ Ko, float* __restrict__ Vo)
{
    const int z = blockIdx.z;
    const float* W    = (z == 0) ? qp : (z == 1) ? kp : vp;
    const float* bias = (z == 0) ? qb : (z == 1) ? kb : vb;
    float* Out        = (z == 0) ? Qo : (z == 1) ? Ko : Vo;

    const int bh = blockIdx.y;
    const int b = bh >> 3, h = bh & 7;
    const int n0 = blockIdx.x * 64;

    const float* xb = x + ((size_t)b * NN + n0) * ND;
    const float* Wh = W + (size_t)h * ND * KD;

    __shared__ float xs[32][64];   // [d][r]  (x tile transposed)
    __shared__ float wsm[32][64];  // [d][k]

    const int t = threadIdx.x;
    const int ty = t >> 4, tx = t & 15;

    float acc[4][4] = {};

    for (int d0 = 0; d0 < ND; d0 += 32) {
        {
            const int r = t >> 2;
            const int dd0 = (t & 3) * 8;
            const float* src = xb + (size_t)r * ND + d0 + dd0;
            float4 v0 = *(const float4*)src;
            float4 v1 = *(const float4*)(src + 4);
            xs[dd0+0][r]=v0.x; xs[dd0+1][r]=v0.y; xs[dd0+2][r]=v0.z; xs[dd0+3][r]=v0.w;
            xs[dd0+4][r]=v1.x; xs[dd0+5][r]=v1.y; xs[dd0+6][r]=v1.z; xs[dd0+7][r]=v1.w;
        }
        {
            const int dd = t >> 3;
            const int c0 = (t & 7) * 8;
            const float* src = Wh + (size_t)(d0 + dd) * KD + c0;
            *(float4*)&wsm[dd][c0]     = *(const float4*)src;
            *(float4*)&wsm[dd][c0 + 4] = *(const float4*)(src + 4);
        }
        __syncthreads();
        #pragma unroll
        for (int kk = 0; kk < 32; ++kk) {
            float4 a4 = *(const float4*)&xs[kk][ty * 4];
            float4 b4 = *(const float4*)&wsm[kk][tx * 4];
            float av[4] = {a4.x, a4.y, a4.z, a4.w};
            float bv[4] = {b4.x, b4.y, b4.z, b4.w};
            #pragma unroll
            for (int i = 0; i < 4; ++i)
                #pragma unroll
                for (int j = 0; j < 4; ++j)
                    acc[i][j] = fmaf(av[i], bv[j], acc[i][j]);
        }
        __syncthreads();
    }

    float4 bv4 = *(const float4*)&bias[h * KD + tx * 4];
    float bb[4] = {bv4.x, bv4.y, bv4.z, bv4.w};
    float* ob = Out + ((size_t)bh * NN + n0) * KD;
    #pragma unroll
    for (int i = 0; i < 4; ++i) {
        float4 o;
        o.x = acc[i][0] + bb[0];
        o.y = acc[i][1] + bb[1];
        o.z = acc[i][2] + bb[2];
        o.w = acc[i][3] + bb[3];
        *(float4*)&ob[(size_t)(ty * 4 + i) * KD + tx * 4] = o;
    }
}

// ---------------- flash attention with RBF band mask
// Block: 64 query rows of one (b,h); loops over 32-wide key tiles.
// Writes merged head output Obuf[b][n][k*NH + h].
__global__ __launch_bounds__(256) void attn_kernel(
    const float* __restrict__ Qg, const float* __restrict__ Kg, const float* __restrict__ Vg,
    const float* __restrict__ coords, float* __restrict__ Obuf, HeadConsts hc)
{
    const int bh = blockIdx.y;
    const int b = bh >> 3, h = bh & 7;
    const int n0 = blockIdx.x * 64;
    const float inv2s2 = hc.inv2s2[h];

    __shared__ float Qs[64][64];   // [k][r]  (transposed)
    __shared__ float Ks[64][34];   // [k][m]  (transposed, padded)
    __shared__ float Vs[32][64];   // [m][k]
    __shared__ float Ps[32][68];   // [m][r]  (padded)
    __shared__ float cmx[32], cmy[32], cmz[32];

    const int t = threadIdx.x;
    const int ty = t >> 4, tx = t & 15;

    {   // Q tile -> LDS transposed
        const int r = t >> 2;
        const int k0 = (t & 3) * 16;
        const float* src = Qg + ((size_t)bh * NN + n0 + r) * KD + k0;
        #pragma unroll
        for (int q = 0; q < 4; ++q) {
            float4 v = *(const float4*)(src + q * 4);
            Qs[k0 + q*4 + 0][r] = v.x;
            Qs[k0 + q*4 + 1][r] = v.y;
            Qs[k0 + q*4 + 2][r] = v.z;
            Qs[k0 + q*4 + 3][r] = v.w;
        }
    }
    float qx[4], qy[4], qz[4];
    #pragma unroll
    for (int i = 0; i < 4; ++i) {
        const float* c = coords + ((size_t)b * NN + n0 + ty * 4 + i) * 3;
        qx[i] = c[0]; qy[i] = c[1]; qz[i] = c[2];
    }

    float m_run[4], l_run[4], o_acc[4][4];
    #pragma unroll
    for (int i = 0; i < 4; ++i) {
        m_run[i] = NEG_INF; l_run[i] = 0.f;
        #pragma unroll
        for (int j = 0; j < 4; ++j) o_acc[i][j] = 0.f;
    }

    for (int mt = 0; mt < NN / 32; ++mt) {
        const int m0 = mt * 32;
        __syncthreads();   // previous PV done before overwriting tiles
        {
            const int m = t >> 3;
            const int k0 = (t & 7) * 8;
            const float* srcK = Kg + ((size_t)bh * NN + m0 + m) * KD + k0;
            float4 v0 = *(const float4*)srcK;
            float4 v1 = *(const float4*)(srcK + 4);
            Ks[k0+0][m]=v0.x; Ks[k0+1][m]=v0.y; Ks[k0+2][m]=v0.z; Ks[k0+3][m]=v0.w;
            Ks[k0+4][m]=v1.x; Ks[k0+5][m]=v1.y; Ks[k0+6][m]=v1.z; Ks[k0+7][m]=v1.w;
            const float* srcV = Vg + ((size_t)bh * NN + m0 + m) * KD + k0;
            *(float4*)&Vs[m][k0]     = *(const float4*)srcV;
            *(float4*)&Vs[m][k0 + 4] = *(const float4*)(srcV + 4);
        }
        if (t < 32) {
            const float* c = coords + ((size_t)b * NN + m0 + t) * 3;
            cmx[t] = c[0]; cmy[t] = c[1]; cmz[t] = c[2];
        }
        __syncthreads();

        // S tile [64 rows][32 cols], 4x2 per thread
        float s[4][2] = {};
        #pragma unroll
        for (int kk = 0; kk < 64; ++kk) {
            float4 a4 = *(const float4*)&Qs[kk][ty * 4];
            float2 b2 = *(const float2*)&Ks[kk][tx * 2];
            float av[4] = {a4.x, a4.y, a4.z, a4.w};
            float bv[2] = {b2.x, b2.y};
            #pragma unroll
            for (int i = 0; i < 4; ++i)
                #pragma unroll
                for (int j = 0; j < 2; ++j)
                    s[i][j] = fmaf(av[i], bv[j], s[i][j]);
        }

        // RBF band mask + logits  (beta*log(rbf) == -2*d2*inv2s2 inside band)
        float p[4][2], tmax[4];
        #pragma unroll
        for (int i = 0; i < 4; ++i) {
            tmax[i] = NEG_INF;
            #pragma unroll
            for (int j = 0; j < 2; ++j) {
                const int mc = tx * 2 + j;
                const float dx = qx[i] - cmx[mc];
                const float dy = qy[i] - cmy[mc];
                const float dz = qz[i] - cmz[mc];
                const float d2 = dx*dx + dy*dy + dz*dz;
                const float e = d2 * inv2s2;
                const float rbf = __expf(-e);
                const bool valid = (rbf >= 0.01f) && (rbf <= 0.99f);
                const float lg = valid ? fmaf(s[i][j], 0.125f, -2.0f * e) : NEG_INF;
                p[i][j] = lg;
                tmax[i] = fmaxf(tmax[i], lg);
            }
        }
        // row max across the 16 tx lanes (rows live in lanes with equal ty)
        #pragma unroll
        for (int i = 0; i < 4; ++i) {
            float v = tmax[i];
            v = fmaxf(v, __shfl_xor(v, 1));
            v = fmaxf(v, __shfl_xor(v, 2));
            v = fmaxf(v, __shfl_xor(v, 4));
            v = fmaxf(v, __shfl_xor(v, 8));
            tmax[i] = v;
        }
        #pragma unroll
        for (int i = 0; i < 4; ++i) {
            const float mnew = fmaxf(m_run[i], tmax[i]);
            float scale;
            if (mnew == NEG_INF) scale = 1.0f;           // fully-masked so far
            else scale = __expf(m_run[i] - mnew);        // expf(-inf)=0 ok
            m_run[i] = mnew;
            float rs = 0.f;
            #pragma unroll
            for (int j = 0; j < 2; ++j) {
                const float pv = (p[i][j] == NEG_INF) ? 0.f : __expf(p[i][j] - mnew);
                p[i][j] = pv;
                rs += pv;
            }
            rs += __shfl_xor(rs, 1); rs += __shfl_xor(rs, 2);
            rs += __shfl_xor(rs, 4); rs += __shfl_xor(rs, 8);
            l_run[i] = l_run[i] * scale + rs;
            #pragma unroll
            for (int j = 0; j < 4; ++j) o_acc[i][j] *= scale;
        }
        // P -> LDS transposed [m][r]
        #pragma unroll
        for (int i = 0; i < 4; ++i)
            #pragma unroll
            for (int j = 0; j < 2; ++j)
                Ps[tx * 2 + j][ty * 4 + i] = p[i][j];
        __syncthreads();

        // O += P @ V  (4x4 per thread: rows ty*4+i, k-cols tx*4+j)
        #pragma unroll
        for (int mm = 0; mm < 32; ++mm) {
            float4 a4 = *(const float4*)&Ps[mm][ty * 4];
            float4 b4 = *(const float4*)&Vs[mm][tx * 4];
            float av[4] = {a4.x, a4.y, a4.z, a4.w};
            float bv[4] = {b4.x, b4.y, b4.z, b4.w};
            #pragma unroll
            for (int i = 0; i < 4; ++i)
                #pragma unroll
                for (int j = 0; j < 4; ++j)
                    o_acc[i][j] = fmaf(av[i], bv[j], o_acc[i][j]);
        }
    }

    // epilogue: normalize and write interleaved (k*NH + h)
    #pragma unroll
    for (int i = 0; i < 4; ++i) {
        const int n = n0 + ty * 4 + i;
        const float invl = (l_run[i] > 0.f) ? 1.0f / l_run[i] : 0.f;
        float* dst = Obuf + ((size_t)b * NN + n) * ND + h;
        #pragma unroll
        for (int j = 0; j < 4; ++j)
            dst[(size_t)(tx * 4 + j) * NH] = o_acc[i][j] * invl;
    }
}

__device__ inline float gelu_tanh(float v) {
    const float kA = 0.7978845608028654f;  // sqrt(2/pi)
    const float u = kA * (v + 0.044715f * v * v * v);
    return 0.5f * v * (1.0f + tanhf(u));
}

// ---------------- C[M,Nc] = A[M,Ka] @ B[Nc,Ka]^T  (+bias)(+gelu)
template<int EPI>  // 0 = plain, 1 = +bias, 2 = +bias+gelu
__global__ __launch_bounds__(256) void gemm_nt_kernel(
    const float* __restrict__ A, const float* __restrict__ Bm,
    const float* __restrict__ bias, float* __restrict__ C,
    int M, int Nc, int Ka)
{
    const int r0 = blockIdx.x * 64;
    const int c0b = blockIdx.y * 64;
    __shared__ float As[32][64];  // [d][r]
    __shared__ float Bs[32][64];  // [d][c]
    const int t = threadIdx.x;
    const int ty = t >> 4, tx = t & 15;
    float acc[4][4] = {};

    for (int d0 = 0; d0 < Ka; d0 += 32) {
        const int r = t >> 2;
        const int dd0 = (t & 3) * 8;
        {
            const float* src = A + (size_t)(r0 + r) * Ka + d0 + dd0;
            float4 v0 = *(const float4*)src;
            float4 v1 = *(const float4*)(src + 4);
            As[dd0+0][r]=v0.x; As[dd0+1][r]=v0.y; As[dd0+2][r]=v0.z; As[dd0+3][r]=v0.w;
            As[dd0+4][r]=v1.x; As[dd0+5][r]=v1.y; As[dd0+6][r]=v1.z; As[dd0+7][r]=v1.w;
        }
        {
            const float* src = Bm + (size_t)(c0b + r) * Ka + d0 + dd0;
            float4 v0 = *(const float4*)src;
            float4 v1 = *(const float4*)(src + 4);
            Bs[dd0+0][r]=v0.x; Bs[dd0+1][r]=v0.y; Bs[dd0+2][r]=v0.z; Bs[dd0+3][r]=v0.w;
            Bs[dd0+4][r]=v1.x; Bs[dd0+5][r]=v1.y; Bs[dd0+6][r]=v1.z; Bs[dd0+7][r]=v1.w;
        }
        __syncthreads();
        #pragma unroll
        for (int kk = 0; kk < 32; ++kk) {
            float4 a4 = *(const float4*)&As[kk][ty * 4];
            float4 b4 = *(const float4*)&Bs[kk][tx * 4];
            float av[4] = {a4.x, a4.y, a4.z, a4.w};
            float bv[4] = {b4.x, b4.y, b4.z, b4.w};
            #pragma unroll
            for (int i = 0; i < 4; ++i)
                #pragma unroll
                for (int j = 0; j < 4; ++j)
                    acc[i][j] = fmaf(av[i], bv[j], acc[i][j]);
        }
        __syncthreads();
    }

    float bb[4] = {0.f, 0.f, 0.f, 0.f};
    if (EPI >= 1) {
        float4 b4 = *(const float4*)&bias[c0b + tx * 4];
        bb[0] = b4.x; bb[1] = b4.y; bb[2] = b4.z; bb[3] = b4.w;
    }
    #pragma unroll
    for (int i = 0; i < 4; ++i) {
        float vals[4];
        #pragma unroll
        for (int j = 0; j < 4; ++j) {
            float v = acc[i][j] + bb[j];
            if (EPI == 2) v = gelu_tanh(v);
            vals[j] = v;
        }
        float4 o; o.x = vals[0]; o.y = vals[1]; o.z = vals[2]; o.w = vals[3];
        *(float4*)&C[(size_t)(r0 + ty * 4 + i) * Nc + c0b + tx * 4] = o;
    }
}

// ---------------- out = LayerNorm(a + b) * g + beta, one wave per 512-wide row
__global__ __launch_bounds__(256) void add_ln_kernel(
    const float* __restrict__ a, const float* __restrict__ bsrc,
    const float* __restrict__ g, const float* __restrict__ bt,
    float* __restrict__ out)
{
    const int lane = threadIdx.x & 63;
    const int row = blockIdx.x * 4 + (threadIdx.x >> 6);
    const float* pa = a + (size_t)row * ND + lane * 8;
    const float* pb = bsrc + (size_t)row * ND + lane * 8;

    float v[8];
    {
        float4 a0 = *(const float4*)pa;
        float4 a1 = *(const float4*)(pa + 4);
        float4 b0 = *(const float4*)pb;
        float4 b1 = *(const float4*)(pb + 4);
        v[0]=a0.x+b0.x; v[1]=a0.y+b0.y; v[2]=a0.z+b0.z; v[3]=a0.w+b0.w;
        v[4]=a1.x+b1.x; v[5]=a1.y+b1.y; v[6]=a1.z+b1.z; v[7]=a1.w+b1.w;
    }
    float s = 0.f;
    #pragma unroll
    for (int k = 0; k < 8; ++k) s += v[k];
    #pragma unroll
    for (int m = 1; m <= 32; m <<= 1) s += __shfl_xor(s, m);
    const float mean = s * (1.0f / ND);

    float vs = 0.f;
    #pragma unroll
    for (int k = 0; k < 8; ++k) { const float d = v[k] - mean; vs += d * d; }
    #pragma unroll
    for (int m = 1; m <= 32; m <<= 1) vs += __shfl_xor(vs, m);
    const float rstd = rsqrtf(vs * (1.0f / ND) + 1e-5f);

    float4 g0 = *(const float4*)(g + lane * 8);
    float4 g1 = *(const float4*)(g + lane * 8 + 4);
    float4 t0 = *(const float4*)(bt + lane * 8);
    float4 t1 = *(const float4*)(bt + lane * 8 + 4);
    float gg[8] = {g0.x,g0.y,g0.z,g0.w,g1.x,g1.y,g1.z,g1.w};
    float tb[8] = {t0.x,t0.y,t0.z,t0.w,t1.x,t1.y,t1.z,t1.w};

    float o[8];
    #pragma unroll
    for (int k = 0; k < 8; ++k) o[k] = (v[k] - mean) * rstd * gg[k] + tb[k];
    float4 w0; w0.x=o[0]; w0.y=o[1]; w0.z=o[2]; w0.w=o[3];
    float4 w1; w1.x=o[4]; w1.y=o[5]; w1.z=o[6]; w1.w=o[7];
    float* po = out + (size_t)row * ND + lane * 8;
    *(float4*)po = w0;
    *(float4*)(po + 4) = w1;
}

extern "C" void kernel_launch(void* const* d_in, const int* in_sizes, int n_in,
                              void* d_out, int out_size, void* d_ws, size_t ws_size,
                              hipStream_t stream)
{
    const float* x      = (const float*)d_in[0];
    const float* coords = (const float*)d_in[1];
    const float* qp     = (const float*)d_in[2];
    const float* kp     = (const float*)d_in[3];
    const float* vp     = (const float*)d_in[4];
    const float* qb     = (const float*)d_in[5];
    const float* kb     = (const float*)d_in[6];
    const float* vb     = (const float*)d_in[7];
    const float* w_out  = (const float*)d_in[8];
    const float* ln1g   = (const float*)d_in[9];
    const float* ln1b   = (const float*)d_in[10];
    const float* w1     = (const float*)d_in[11];
    const float* b1     = (const float*)d_in[12];
    const float* w2     = (const float*)d_in[13];
    const float* b2     = (const float*)d_in[14];
    const float* ln2g   = (const float*)d_in[15];
    const float* ln2b   = (const float*)d_in[16];
    float* out = (float*)d_out;

    const size_t SZ = (size_t)NB * NN * ND;  // 2,097,152 floats (== BH*N*KD)
    float* ws = (float*)d_ws;
    float* Qb  = ws;
    float* Kb  = ws + SZ;
    float* Vb  = ws + 2 * SZ;
    float* Ob  = ws + 3 * SZ;
    float* Hb  = ws + 4 * SZ;   // 2*SZ floats (4096 x 1024)
    float* Att = Qb;            // reuse: Q dead after attention
    float* X1  = Kb;            // reuse: K dead after attention
    float* Ffn = Vb;            // reuse: V dead after attention

    HeadConsts hc;
    for (int i = 0; i < NH; ++i) {
        const double sg = 1.0 + 5.0 * (pow(20.0, (double)i / 7.0) - 1.0) / 19.0;
        hc.inv2s2[i] = (float)(1.0 / (2.0 * sg * sg));
    }

    qkv_kernel<<<dim3(16, 32, 3), 256, 0, stream>>>(x, qp, kp, vp, qb, kb, vb, Qb, Kb, Vb);
    attn_kernel<<<dim3(16, 32), 256, 0, stream>>>(Qb, Kb, Vb, coords, Ob, hc);
    gemm_nt_kernel<0><<<dim3(64, 8), 256, 0, stream>>>(Ob, w_out, nullptr, Att, 4096, 512, 512);
    add_ln_kernel<<<1024, 256, 0, stream>>>(x, Att, ln1g, ln1b, X1);
    gemm_nt_kernel<2><<<dim3(64, 16), 256, 0, stream>>>(X1, w1, b1, Hb, 4096, 1024, 512);
    gemm_nt_kernel<1><<<dim3(64, 8), 256, 0, stream>>>(Hb, w2, b2, Ffn, 4096, 512, 1024);
    add_ln_kernel<<<1024, 256, 0, stream>>>(X1, Ffn, ln2g, ln2b, out);
}

// Round 2
// 153.056 us; speedup vs baseline: 4.2530x; 4.2530x over previous
//
#include <hip/hip_runtime.h>
#include <cmath>

typedef short s16x8 __attribute__((ext_vector_type(8)));
typedef float f32x4 __attribute__((ext_vector_type(4)));
typedef unsigned short u16;

#define MFMA(a, b, c) __builtin_amdgcn_mfma_f32_16x16x32_bf16((a), (b), (c), 0, 0, 0)
#define NEG_INF (-__builtin_inff())

__device__ inline u16 f2b(float f) {
    union { float f; unsigned u; } v; v.f = f;
    unsigned r = v.u + 0x7fffu + ((v.u >> 16) & 1u);
    return (u16)(r >> 16);
}

// ============================ prep: fp32 -> bf16 (+ transposes/permutes) =====
// xb[4096][512]; Bqkv[1536][512] (row c = z*512+h*64+k, col d);
// w_outp[512][512] (col h*64+k <- k*8+h); w1b[1024][512]; w2b[512][1024]
__global__ __launch_bounds__(256) void prep_kernel(
    const float* __restrict__ x,
    const float* __restrict__ qp, const float* __restrict__ kp, const float* __restrict__ vp,
    const float* __restrict__ w_out, const float* __restrict__ w1, const float* __restrict__ w2,
    u16* __restrict__ xb, u16* __restrict__ Bqkv, u16* __restrict__ w_outp,
    u16* __restrict__ w1b, u16* __restrict__ w2b)
{
    const int NX = 4096 * 512;      // 2097152
    const int NQKV = 3 * 8 * 512 * 64;  // 786432
    const int NWO = 512 * 512;      // 262144
    const int NW1 = 1024 * 512;     // 524288
    const int NW2 = 512 * 1024;     // 524288
    const int TOT = NX + NQKV + NWO + NW1 + NW2;   // 4194304
    for (int i = blockIdx.x * 256 + threadIdx.x; i < TOT; i += gridDim.x * 256) {
        int j = i;
        if (j < NX) { xb[j] = f2b(x[j]); continue; }
        j -= NX;
        if (j < NQKV) {
            const int k = j & 63, d = (j >> 6) & 511, zh = j >> 15;  // zh 0..23
            const int z = zh >> 3, h = zh & 7;
            const float* W = (z == 0) ? qp : (z == 1) ? kp : vp;
            const float v = W[h * 32768 + d * 64 + k];
            const int c = z * 512 + h * 64 + k;
            Bqkv[c * 512 + d] = f2b(v);
            continue;
        }
        j -= NQKV;
        if (j < NWO) {
            const int oc = j & 511, row = j >> 9;
            const int h = oc >> 6, k = oc & 63;
            w_outp[j] = f2b(w_out[row * 512 + k * 8 + h]);
            continue;
        }
        j -= NWO;
        if (j < NW1) { w1b[j] = f2b(w1[j]); continue; }
        j -= NW1;
        w2b[j] = f2b(w2[j]);
    }
}

// ============================ shared MFMA GEMM core ==========================
// C-tile 128x128 at (r0,c0).  A[M][K], B[N][K] bf16-bits, K = ktiles*64.
// 256 threads = 4 waves, wave (wid&1, wid>>1) owns a 64x64 quadrant as 4x4
// fragments of 16x16.  acc[fr][fc]: D-layout col=lane&15, row=(lane>>4)*4+reg.
__device__ inline void gemm_core(const u16* __restrict__ A, const u16* __restrict__ B,
                                 int K, int ktiles, int r0, int c0,
                                 u16 (*As)[72], u16 (*Bs)[72], f32x4 acc[4][4])
{
    const int t = threadIdx.x;
    const int lane = t & 63, wid = t >> 6;
    const int wr = (wid & 1) * 64, wc = (wid >> 1) * 64;
    const int l15 = lane & 15, lg = lane >> 4;

    const f32x4 zero = {0.f, 0.f, 0.f, 0.f};
    #pragma unroll
    for (int fr = 0; fr < 4; ++fr)
        #pragma unroll
        for (int fc = 0; fc < 4; ++fc) acc[fr][fc] = zero;

    for (int kt = 0; kt < ktiles; ++kt) {
        const int k0 = kt * 64;
        __syncthreads();
        #pragma unroll
        for (int i = 0; i < 4; ++i) {
            const int id = t + 256 * i;          // 0..1023
            const int row = id >> 3, c8 = (id & 7) * 8;
            s16x8 va = *(const s16x8*)(A + (size_t)(r0 + row) * K + k0 + c8);
            *(s16x8*)&As[row][c8] = va;
            s16x8 vb = *(const s16x8*)(B + (size_t)(c0 + row) * K + k0 + c8);
            *(s16x8*)&Bs[row][c8] = vb;
        }
        __syncthreads();
        #pragma unroll
        for (int ks = 0; ks < 2; ++ks) {
            s16x8 af[4], bf[4];
            #pragma unroll
            for (int f = 0; f < 4; ++f) {
                af[f] = *(const s16x8*)&As[wr + f * 16 + l15][ks * 32 + lg * 8];
                bf[f] = *(const s16x8*)&Bs[wc + f * 16 + l15][ks * 32 + lg * 8];
            }
            #pragma unroll
            for (int fr = 0; fr < 4; ++fr)
                #pragma unroll
                for (int fc = 0; fc < 4; ++fc)
                    acc[fr][fc] = MFMA(af[fr], bf[fc], acc[fr][fc]);
        }
    }
}

// ============================ QKV GEMM: C[4096][1536] -> Q/K planar, V transposed
__global__ __launch_bounds__(256) void gemm_qkv_kernel(
    const u16* __restrict__ xb, const u16* __restrict__ Bqkv,
    const float* __restrict__ qb, const float* __restrict__ kb, const float* __restrict__ vb,
    u16* __restrict__ Qb, u16* __restrict__ Kb, u16* __restrict__ Vtb)
{
    __shared__ u16 As[128][72], Bs[128][72];
    f32x4 acc[4][4];
    const int r0 = blockIdx.x * 128, c0 = blockIdx.y * 128;
    gemm_core(xb, Bqkv, 512, 8, r0, c0, As, Bs, acc);

    const int t = threadIdx.x, lane = t & 63, wid = t >> 6;
    const int wr = (wid & 1) * 64, wc = (wid >> 1) * 64;
    const int l15 = lane & 15, lg = lane >> 4;

    #pragma unroll
    for (int fc = 0; fc < 4; ++fc) {
        const int gc = c0 + wc + fc * 16 + l15;
        const int z = gc >> 9;                  // 0=q 1=k 2=v (uniform per fragment)
        const int hk = gc & 511;                // h*64+k
        const int h = hk >> 6, k = gc & 63;
        const float bias = (z == 0 ? qb : z == 1 ? kb : vb)[hk];
        #pragma unroll
        for (int fr = 0; fr < 4; ++fr) {
            #pragma unroll
            for (int r = 0; r < 4; ++r) {
                const int grow = r0 + wr + fr * 16 + lg * 4 + r;
                const int b = grow >> 10, n = grow & 1023;
                const int bh = b * 8 + h;
                const u16 val = f2b(acc[fr][fc][r] + bias);
                if (z == 0)      Qb[(size_t)bh * 65536 + n * 64 + k] = val;
                else if (z == 1) Kb[(size_t)bh * 65536 + n * 64 + k] = val;
                else             Vtb[(size_t)bh * 65536 + k * 1024 + n] = val;
            }
        }
    }
}

// ============================ generic GEMM epilogues =========================
// EPI 0: C=f32           (out-proj)
// EPI 1: C=f32 + bias    (ffn2)
// EPI 2: C=bf16 + bias + gelu (ffn1)
template<int EPI>
__global__ __launch_bounds__(256) void gemm_kernel(
    const u16* __restrict__ A, const u16* __restrict__ B, const float* __restrict__ bias,
    float* __restrict__ Cf, u16* __restrict__ Cb, int N, int ktiles)
{
    __shared__ u16 As[128][72], Bs[128][72];
    f32x4 acc[4][4];
    const int r0 = blockIdx.x * 128, c0 = blockIdx.y * 128;
    gemm_core(A, B, ktiles * 64, ktiles, r0, c0, As, Bs, acc);

    const int t = threadIdx.x, lane = t & 63, wid = t >> 6;
    const int wr = (wid & 1) * 64, wc = (wid >> 1) * 64;
    const int l15 = lane & 15, lg = lane >> 4;

    #pragma unroll
    for (int fc = 0; fc < 4; ++fc) {
        const int gc = c0 + wc + fc * 16 + l15;
        const float bv = (EPI >= 1) ? bias[gc] : 0.f;
        #pragma unroll
        for (int fr = 0; fr < 4; ++fr) {
            #pragma unroll
            for (int r = 0; r < 4; ++r) {
                const int grow = r0 + wr + fr * 16 + lg * 4 + r;
                float v = acc[fr][fc][r] + bv;
                if (EPI == 2) {
                    const float u = 0.7978845608028654f * (v + 0.044715f * v * v * v);
                    v = 0.5f * v * (1.0f + tanhf(u));
                    Cb[(size_t)grow * N + gc] = f2b(v);
                } else {
                    Cf[(size_t)grow * N + gc] = v;
                }
            }
        }
    }
}

// ============================ flash attention (MFMA) =========================
struct AttnParams { float g[8], lo[8], hi[8]; };

__global__ __launch_bounds__(256) void attn_kernel(
    const u16* __restrict__ Qb, const u16* __restrict__ Kb, const u16* __restrict__ Vtb,
    const float* __restrict__ coords, u16* __restrict__ Ob, AttnParams prm)
{
    __shared__ u16 Ks[64][72];      // [m][k]
    __shared__ u16 Vs[64][72];      // [k][m]  (V transposed)
    __shared__ u16 Ps[64][72];      // [q][m]  (wave-private row bands)
    __shared__ float cmx[64], cmy[64], cmz[64];

    const int bh = blockIdx.y, b = bh >> 3, h = bh & 7;
    const int n0 = blockIdx.x * 64;
    const float g = prm.g[h], lo = prm.lo[h], hi = prm.hi[h];

    const int t = threadIdx.x, lane = t & 63, wid = t >> 6;
    const int l15 = lane & 15, lg = lane >> 4;
    const int wq0 = wid * 16;

    // Q fragments (16 q-rows x 64, 2 K-steps) held in registers
    s16x8 qf[2];
    {
        const u16* qp_ = Qb + (size_t)bh * 65536 + (size_t)(n0 + wq0 + l15) * 64;
        qf[0] = *(const s16x8*)(qp_ + lg * 8);
        qf[1] = *(const s16x8*)(qp_ + 32 + lg * 8);
    }
    float qx[4], qy[4], qz[4];
    #pragma unroll
    for (int r = 0; r < 4; ++r) {
        const float* c = coords + ((size_t)b * 1024 + n0 + wq0 + lg * 4 + r) * 3;
        qx[r] = c[0]; qy[r] = c[1]; qz[r] = c[2];
    }

    float m_run[4], l_run[4];
    f32x4 o_acc[4];
    const f32x4 zero = {0.f, 0.f, 0.f, 0.f};
    #pragma unroll
    for (int r = 0; r < 4; ++r) { m_run[r] = NEG_INF; l_run[r] = 0.f; }
    #pragma unroll
    for (int kf = 0; kf < 4; ++kf) o_acc[kf] = zero;

    for (int mt = 0; mt < 16; ++mt) {
        const int m0 = mt * 64;
        __syncthreads();                       // prior PV reads done
        #pragma unroll
        for (int i = 0; i < 2; ++i) {
            const int id = t + 256 * i;        // 0..511
            const int row = id >> 3, c8 = (id & 7) * 8;
            s16x8 kv = *(const s16x8*)(Kb + (size_t)bh * 65536 + (size_t)(m0 + row) * 64 + c8);
            *(s16x8*)&Ks[row][c8] = kv;
            s16x8 vv = *(const s16x8*)(Vtb + (size_t)bh * 65536 + (size_t)row * 1024 + m0 + c8);
            *(s16x8*)&Vs[row][c8] = vv;
        }
        if (t < 64) {
            const float* c = coords + ((size_t)b * 1024 + m0 + t) * 3;
            cmx[t] = c[0]; cmy[t] = c[1]; cmz[t] = c[2];
        }
        __syncthreads();

        // S = Q K^T  (4 m-fragments per wave)
        f32x4 s[4];
        #pragma unroll
        for (int mf = 0; mf < 4; ++mf) {
            s16x8 kf0 = *(const s16x8*)&Ks[mf * 16 + l15][lg * 8];
            s16x8 kf1 = *(const s16x8*)&Ks[mf * 16 + l15][32 + lg * 8];
            f32x4 a = zero;
            a = MFMA(qf[0], kf0, a);
            a = MFMA(qf[1], kf1, a);
            s[mf] = a;
        }

        // masked logits + online softmax (fp32 d2 from fp32 coords)
        float p[4][4];       // [mf][r]
        float tmax[4] = {NEG_INF, NEG_INF, NEG_INF, NEG_INF};
        #pragma unroll
        for (int mf = 0; mf < 4; ++mf) {
            const int mloc = mf * 16 + l15;
            const float mx = cmx[mloc], my = cmy[mloc], mz = cmz[mloc];
            #pragma unroll
            for (int r = 0; r < 4; ++r) {
                const float dx = qx[r] - mx, dy = qy[r] - my, dz = qz[r] - mz;
                const float d2 = fmaf(dx, dx, fmaf(dy, dy, dz * dz));
                const bool valid = (d2 >= lo) && (d2 <= hi);
                const float lgt = fmaf(s[mf][r], 0.125f, d2 * g);
                const float v = valid ? lgt : NEG_INF;
                p[mf][r] = v;
                tmax[r] = fmaxf(tmax[r], v);
            }
        }
        #pragma unroll
        for (int r = 0; r < 4; ++r) {
            float v = tmax[r];
            v = fmaxf(v, __shfl_xor(v, 1));
            v = fmaxf(v, __shfl_xor(v, 2));
            v = fmaxf(v, __shfl_xor(v, 4));
            v = fmaxf(v, __shfl_xor(v, 8));
            const float mnew = fmaxf(m_run[r], v);
            const float scale = (mnew == NEG_INF) ? 1.f : __expf(m_run[r] - mnew);
            m_run[r] = mnew;
            float rs = 0.f;
            #pragma unroll
            for (int mf = 0; mf < 4; ++mf) {
                const float pv = (p[mf][r] == NEG_INF) ? 0.f : __expf(p[mf][r] - mnew);
                p[mf][r] = pv;
                rs += pv;
            }
            rs += __shfl_xor(rs, 1); rs += __shfl_xor(rs, 2);
            rs += __shfl_xor(rs, 4); rs += __shfl_xor(rs, 8);
            l_run[r] = l_run[r] * scale + rs;
            #pragma unroll
            for (int kf = 0; kf < 4; ++kf) o_acc[kf][r] *= scale;
        }
        // P -> LDS (own wave's 16 rows; no barrier needed)
        #pragma unroll
        for (int mf = 0; mf < 4; ++mf)
            #pragma unroll
            for (int r = 0; r < 4; ++r)
                Ps[wq0 + lg * 4 + r][mf * 16 + l15] = f2b(p[mf][r]);

        // O += P V  (inner dim m: 2 K-steps)
        #pragma unroll
        for (int ms = 0; ms < 2; ++ms) {
            s16x8 pa = *(const s16x8*)&Ps[wq0 + l15][ms * 32 + lg * 8];
            #pragma unroll
            for (int kf = 0; kf < 4; ++kf) {
                s16x8 vb_ = *(const s16x8*)&Vs[kf * 16 + l15][ms * 32 + lg * 8];
                o_acc[kf] = MFMA(pa, vb_, o_acc[kf]);
            }
        }
    }

    // normalize + write planar O[b,n][h*64+k] (bf16)
    #pragma unroll
    for (int kf = 0; kf < 4; ++kf) {
        #pragma unroll
        for (int r = 0; r < 4; ++r) {
            const int n = n0 + wq0 + lg * 4 + r;
            const float invl = (l_run[r] > 0.f) ? 1.f / l_run[r] : 0.f;
            Ob[((size_t)b * 1024 + n) * 512 + h * 64 + kf * 16 + l15] = f2b(o_acc[kf][r] * invl);
        }
    }
}

// ============================ fused add + LayerNorm ==========================
template<bool WB16>
__global__ __launch_bounds__(256) void add_ln_kernel(
    const float* __restrict__ a, const float* __restrict__ bsrc,
    const float* __restrict__ g, const float* __restrict__ bt,
    float* __restrict__ out, u16* __restrict__ outb)
{
    const int lane = threadIdx.x & 63;
    const int row = blockIdx.x * 4 + (threadIdx.x >> 6);
    const float* pa = a + (size_t)row * 512 + lane * 8;
    const float* pb = bsrc + (size_t)row * 512 + lane * 8;

    float v[8];
    {
        float4 a0 = *(const float4*)pa;
        float4 a1 = *(const float4*)(pa + 4);
        float4 b0 = *(const float4*)pb;
        float4 b1 = *(const float4*)(pb + 4);
        v[0]=a0.x+b0.x; v[1]=a0.y+b0.y; v[2]=a0.z+b0.z; v[3]=a0.w+b0.w;
        v[4]=a1.x+b1.x; v[5]=a1.y+b1.y; v[6]=a1.z+b1.z; v[7]=a1.w+b1.w;
    }
    float s = 0.f;
    #pragma unroll
    for (int k = 0; k < 8; ++k) s += v[k];
    #pragma unroll
    for (int m = 1; m <= 32; m <<= 1) s += __shfl_xor(s, m);
    const float mean = s * (1.0f / 512.0f);

    float vs = 0.f;
    #pragma unroll
    for (int k = 0; k < 8; ++k) { const float d = v[k] - mean; vs += d * d; }
    #pragma unroll
    for (int m = 1; m <= 32; m <<= 1) vs += __shfl_xor(vs, m);
    const float rstd = rsqrtf(vs * (1.0f / 512.0f) + 1e-5f);

    float4 g0 = *(const float4*)(g + lane * 8);
    float4 g1 = *(const float4*)(g + lane * 8 + 4);
    float4 t0 = *(const float4*)(bt + lane * 8);
    float4 t1 = *(const float4*)(bt + lane * 8 + 4);
    float gg[8] = {g0.x,g0.y,g0.z,g0.w,g1.x,g1.y,g1.z,g1.w};
    float tb[8] = {t0.x,t0.y,t0.z,t0.w,t1.x,t1.y,t1.z,t1.w};

    float o[8];
    #pragma unroll
    for (int k = 0; k < 8; ++k) o[k] = (v[k] - mean) * rstd * gg[k] + tb[k];
    float* po = out + (size_t)row * 512 + lane * 8;
    float4 w0; w0.x=o[0]; w0.y=o[1]; w0.z=o[2]; w0.w=o[3];
    float4 w1; w1.x=o[4]; w1.y=o[5]; w1.z=o[6]; w1.w=o[7];
    *(float4*)po = w0;
    *(float4*)(po + 4) = w1;
    if (WB16) {
        u16* pq = outb + (size_t)row * 512 + lane * 8;
        #pragma unroll
        for (int k = 0; k < 8; ++k) pq[k] = f2b(o[k]);
    }
}

// ============================ launch =========================================
extern "C" void kernel_launch(void* const* d_in, const int* in_sizes, int n_in,
                              void* d_out, int out_size, void* d_ws, size_t ws_size,
                              hipStream_t stream)
{
    const float* x      = (const float*)d_in[0];
    const float* coords = (const float*)d_in[1];
    const float* qp     = (const float*)d_in[2];
    const float* kp     = (const float*)d_in[3];
    const float* vp     = (const float*)d_in[4];
    const float* qbias  = (const float*)d_in[5];
    const float* kbias  = (const float*)d_in[6];
    const float* vbias  = (const float*)d_in[7];
    const float* w_out  = (const float*)d_in[8];
    const float* ln1g   = (const float*)d_in[9];
    const float* ln1b   = (const float*)d_in[10];
    const float* w1     = (const float*)d_in[11];
    const float* b1     = (const float*)d_in[12];
    const float* w2     = (const float*)d_in[13];
    const float* b2     = (const float*)d_in[14];
    const float* ln2g   = (const float*)d_in[15];
    const float* ln2b   = (const float*)d_in[16];
    float* out = (float*)d_out;

    char* W = (char*)d_ws;
    u16*  xb     = (u16*)(W + 0);                    //  4 MiB
    u16*  Bqkv   = (u16*)(W + 4194304);              //  1.5 MiB
    u16*  w_outp = (u16*)(W + 5767168);              //  0.5 MiB
    u16*  w1b    = (u16*)(W + 6291456);              //  1 MiB
    u16*  w2b    = (u16*)(W + 7340032);              //  1 MiB
    u16*  Qb     = (u16*)(W + 8388608);              //  4 MiB
    u16*  Kb     = (u16*)(W + 12582912);             //  4 MiB
    u16*  Vtb    = (u16*)(W + 16777216);             //  4 MiB
    u16*  Ob     = (u16*)(W + 20971520);             //  4 MiB
    float* Att   = (float*)(W + 25165824);           //  8 MiB
    float* X1    = (float*)(W + 33554432);           //  8 MiB
    u16*  Hb     = (u16*)(W + 41943040);             //  8 MiB
    u16*  X1b    = Qb;                               // reuse (Q dead after attn)
    float* Ffn   = (float*)(W + 12582912);           // reuse Kb+Vtb (8 MiB)

    AttnParams prm;
    for (int h = 0; h < 8; ++h) {
        const double sg = 1.0 + 5.0 * (pow(20.0, (double)h / 7.0) - 1.0) / 19.0;
        const double s2 = sg * sg;
        prm.g[h]  = (float)(-1.0 / s2);
        prm.lo[h] = (float)(2.0 * s2 * log(100.0 / 99.0));
        prm.hi[h] = (float)(2.0 * s2 * log(100.0));
    }

    prep_kernel<<<1024, 256, 0, stream>>>(x, qp, kp, vp, w_out, w1, w2,
                                          xb, Bqkv, w_outp, w1b, w2b);
    gemm_qkv_kernel<<<dim3(32, 12), 256, 0, stream>>>(xb, Bqkv, qbias, kbias, vbias,
                                                      Qb, Kb, Vtb);
    attn_kernel<<<dim3(16, 32), 256, 0, stream>>>(Qb, Kb, Vtb, coords, Ob, prm);
    gemm_kernel<0><<<dim3(32, 4), 256, 0, stream>>>(Ob, w_outp, nullptr, Att, nullptr, 512, 8);
    add_ln_kernel<true><<<1024, 256, 0, stream>>>(x, Att, ln1g, ln1b, X1, X1b);
    gemm_kernel<2><<<dim3(32, 8), 256, 0, stream>>>(X1b, w1b, b1, nullptr, Hb, 1024, 8);
    gemm_kernel<1><<<dim3(32, 4), 256, 0, stream>>>(Hb, w2b, b2, Ffn, nullptr, 512, 16);
    add_ln_kernel<false><<<1024, 256, 0, stream>>>(X1, Ffn, ln2g, ln2b, out, nullptr);
}

// Round 3
// 138.698 us; speedup vs baseline: 4.6932x; 1.1035x over previous
//
#include <hip/hip_runtime.h>
#include <cmath>

typedef short s16x8 __attribute__((ext_vector_type(8)));
typedef float f32x4 __attribute__((ext_vector_type(4)));
typedef unsigned short u16;

#define MFMA(a, b, c) __builtin_amdgcn_mfma_f32_16x16x32_bf16((a), (b), (c), 0, 0, 0)
#define NEG_INF (-__builtin_inff())

__device__ inline u16 f2b(float f) {
    union { float f; unsigned u; } v; v.f = f;
    unsigned r = v.u + 0x7fffu + ((v.u >> 16) & 1u);
    return (u16)(r >> 16);
}

// async global->LDS, 16B per lane. LDS dest: wave-uniform base + lane*16.
__device__ inline void glds16(const u16* g, u16* l) {
    __builtin_amdgcn_global_load_lds(
        (const __attribute__((address_space(1))) unsigned int*)g,
        (__attribute__((address_space(3))) unsigned int*)l, 16, 0, 0);
}

// ============================ prep: fp32 -> bf16 (+ transposes/permutes) =====
__global__ __launch_bounds__(256) void prep_kernel(
    const float* __restrict__ x,
    const float* __restrict__ qp, const float* __restrict__ kp, const float* __restrict__ vp,
    const float* __restrict__ w_out, const float* __restrict__ w1, const float* __restrict__ w2,
    u16* __restrict__ xb, u16* __restrict__ Bqkv, u16* __restrict__ w_outp,
    u16* __restrict__ w1b, u16* __restrict__ w2b)
{
    const int NXV = 262144;             // 2097152 / 8 (vectorized x)
    const int NQKV = 786432;
    const int NWO = 262144;
    const int NW1 = 524288;
    const int NW2 = 524288;
    const int TOT = NXV + NQKV + NWO + NW1 + NW2;
    for (int i = blockIdx.x * 256 + threadIdx.x; i < TOT; i += gridDim.x * 256) {
        int j = i;
        if (j < NXV) {
            const int base = j * 8;
            float4 a0 = *(const float4*)(x + base);
            float4 a1 = *(const float4*)(x + base + 4);
            s16x8 o;
            o[0]=f2b(a0.x); o[1]=f2b(a0.y); o[2]=f2b(a0.z); o[3]=f2b(a0.w);
            o[4]=f2b(a1.x); o[5]=f2b(a1.y); o[6]=f2b(a1.z); o[7]=f2b(a1.w);
            *(s16x8*)(xb + base) = o;
            continue;
        }
        j -= NXV;
        if (j < NQKV) {
            const int k = j & 63, d = (j >> 6) & 511, zh = j >> 15;
            const int z = zh >> 3, h = zh & 7;
            const float* W = (z == 0) ? qp : (z == 1) ? kp : vp;
            const float v = W[h * 32768 + d * 64 + k];
            Bqkv[(z * 512 + h * 64 + k) * 512 + d] = f2b(v);
            continue;
        }
        j -= NQKV;
        if (j < NWO) {
            const int oc = j & 511, row = j >> 9;
            const int h = oc >> 6, k = oc & 63;
            w_outp[j] = f2b(w_out[row * 512 + k * 8 + h]);
            continue;
        }
        j -= NWO;
        if (j < NW1) { w1b[j] = f2b(w1[j]); continue; }
        j -= NW1;
        w2b[j] = f2b(w2[j]);
    }
}

// ============================ MFMA GEMM core (m97 structure) =================
// Tile TM x 128, BK=64, 4 waves in 2x2. global_load_lds w/ XOR chunk-swizzle:
// LDS slot (row, c) holds global chunk (row, c^(row&7)); ds_read applies same XOR.
template<int TM>
__device__ inline void gemm_core(const u16* __restrict__ A, const u16* __restrict__ B,
                                 int K, int ktiles, int kstart, int r0, int c0,
                                 u16* As, u16* Bs, f32x4 (&acc)[TM / 32][4])
{
    const int t = threadIdx.x, lane = t & 63, wid = t >> 6;
    const int l15 = lane & 15, lg = lane >> 4, sw = l15 & 7;
    constexpr int FR = TM / 32;
    const int wr = (wid & 1) * (TM / 2), wc = (wid >> 1) * 64;
    constexpr int NA = TM * 8 / 256;    // A-stage issues per thread

    const f32x4 zero = {0.f, 0.f, 0.f, 0.f};
    #pragma unroll
    for (int fr = 0; fr < FR; ++fr)
        #pragma unroll
        for (int fc = 0; fc < 4; ++fc) acc[fr][fc] = zero;

    for (int kt = 0; kt < ktiles; ++kt) {
        const int k0 = kstart + kt * 64;
        __syncthreads();
        #pragma unroll
        for (int i = 0; i < NA; ++i) {
            const int slot = i * 256 + t;
            const int row = slot >> 3, c = slot & 7;
            glds16(A + (size_t)(r0 + row) * K + k0 + ((c ^ (row & 7)) << 3),
                   As + i * 2048 + wid * 512);
        }
        #pragma unroll
        for (int i = 0; i < 4; ++i) {
            const int slot = i * 256 + t;
            const int row = slot >> 3, c = slot & 7;
            glds16(B + (size_t)(c0 + row) * K + k0 + ((c ^ (row & 7)) << 3),
                   Bs + i * 2048 + wid * 512);
        }
        __syncthreads();
        #pragma unroll
        for (int ks = 0; ks < 2; ++ks) {
            const int cc = ((ks * 4 + lg) ^ sw) * 8;
            s16x8 af[FR], bf[4];
            #pragma unroll
            for (int f = 0; f < FR; ++f)
                af[f] = *(const s16x8*)(As + (wr + f * 16 + l15) * 64 + cc);
            #pragma unroll
            for (int f = 0; f < 4; ++f)
                bf[f] = *(const s16x8*)(Bs + (wc + f * 16 + l15) * 64 + cc);
            #pragma unroll
            for (int fr = 0; fr < FR; ++fr)
                #pragma unroll
                for (int fc = 0; fc < 4; ++fc)
                    acc[fr][fc] = MFMA(af[fr], bf[fc], acc[fr][fc]);
        }
    }
}

// ============================ QKV GEMM (TM=64): Q/K planar, V transposed =====
__global__ __launch_bounds__(256) void gemm_qkv_kernel(
    const u16* __restrict__ xb, const u16* __restrict__ Bqkv,
    const float* __restrict__ qb, const float* __restrict__ kb, const float* __restrict__ vb,
    u16* __restrict__ Qb, u16* __restrict__ Kb, u16* __restrict__ Vtb)
{
    __shared__ __align__(16) u16 As[64 * 64];
    __shared__ __align__(16) u16 Bs[128 * 64];
    f32x4 acc[2][4];
    const int r0 = blockIdx.x * 64, c0 = blockIdx.y * 128;
    gemm_core<64>(xb, Bqkv, 512, 8, 0, r0, c0, As, Bs, acc);

    const int t = threadIdx.x, lane = t & 63, wid = t >> 6;
    const int wr = (wid & 1) * 32, wc = (wid >> 1) * 64;
    const int l15 = lane & 15, lg = lane >> 4;

    #pragma unroll
    for (int fc = 0; fc < 4; ++fc) {
        const int gc = c0 + wc + fc * 16 + l15;
        const int z = gc >> 9;
        const int hk = gc & 511;
        const int h = hk >> 6, k = gc & 63;
        const float bias = (z == 0 ? qb : z == 1 ? kb : vb)[hk];
        #pragma unroll
        for (int fr = 0; fr < 2; ++fr) {
            #pragma unroll
            for (int r = 0; r < 4; ++r) {
                const int grow = r0 + wr + fr * 16 + lg * 4 + r;
                const int b = grow >> 10, n = grow & 1023;
                const int bh = b * 8 + h;
                const u16 val = f2b(acc[fr][fc][r] + bias);
                if (z == 0)      Qb[(size_t)bh * 65536 + n * 64 + k] = val;
                else if (z == 1) Kb[(size_t)bh * 65536 + n * 64 + k] = val;
                else             Vtb[(size_t)bh * 65536 + k * 1024 + n] = val;
            }
        }
    }
}

// ============================ generic GEMM (TM=64, optional split-K) =========
// EPI 0: f32 out (partial allowed via blockIdx.z), EPI 2: bf16 + bias + gelu
template<int EPI>
__global__ __launch_bounds__(256) void gemm_kernel(
    const u16* __restrict__ A, const u16* __restrict__ B, const float* __restrict__ bias,
    float* __restrict__ Cf, u16* __restrict__ Cb, int N, int K, int ktiles, size_t pstride)
{
    __shared__ __align__(16) u16 As[64 * 64];
    __shared__ __align__(16) u16 Bs[128 * 64];
    f32x4 acc[2][4];
    const int r0 = blockIdx.x * 64, c0 = blockIdx.y * 128;
    const int kstart = blockIdx.z * ktiles * 64;
    gemm_core<64>(A, B, K, ktiles, kstart, r0, c0, As, Bs, acc);
    float* Cfz = Cf + (size_t)blockIdx.z * pstride;

    const int t = threadIdx.x, lane = t & 63, wid = t >> 6;
    const int wr = (wid & 1) * 32, wc = (wid >> 1) * 64;
    const int l15 = lane & 15, lg = lane >> 4;

    #pragma unroll
    for (int fc = 0; fc < 4; ++fc) {
        const int gc = c0 + wc + fc * 16 + l15;
        const float bv = (EPI == 2) ? bias[gc] : 0.f;
        #pragma unroll
        for (int fr = 0; fr < 2; ++fr) {
            #pragma unroll
            for (int r = 0; r < 4; ++r) {
                const int grow = r0 + wr + fr * 16 + lg * 4 + r;
                float v = acc[fr][fc][r] + bv;
                if (EPI == 2) {
                    const float u = 0.7978845608028654f * (v + 0.044715f * v * v * v);
                    v = 0.5f * v * (1.0f + tanhf(u));
                    Cb[(size_t)grow * N + gc] = f2b(v);
                } else {
                    Cfz[(size_t)grow * N + gc] = v;
                }
            }
        }
    }
}

// ============================ flash attention (MFMA, no KV staging) ==========
struct AttnParams { float g[8], lo[8], hi[8]; };

__global__ __launch_bounds__(256) void attn_kernel(
    const u16* __restrict__ Qb, const u16* __restrict__ Kb, const u16* __restrict__ Vtb,
    const float* __restrict__ coords, u16* __restrict__ Ob, AttnParams prm)
{
    __shared__ float cmx[1024], cmy[1024], cmz[1024];
    __shared__ __align__(16) u16 Ps[4][16][72];

    // XCD-bijective swizzle: 512 blocks, 8 XCDs -> each XCD owns 4 heads' K/V.
    const int wg = blockIdx.x;
    const int swz = (wg & 7) * 64 + (wg >> 3);
    const int bh = swz >> 4;
    const int n0 = (swz & 15) * 64;
    const int b = bh >> 3, h = bh & 7;
    const float g = prm.g[h], lo = prm.lo[h], hi = prm.hi[h];

    const int t = threadIdx.x, lane = t & 63, wid = t >> 6;
    const int l15 = lane & 15, lg = lane >> 4;
    const int wq0 = wid * 16;

    for (int i = t; i < 1024; i += 256) {
        const float* c = coords + ((size_t)b * 1024 + i) * 3;
        cmx[i] = c[0]; cmy[i] = c[1]; cmz[i] = c[2];
    }
    __syncthreads();   // only barrier; main loop is barrier-free

    s16x8 qf[2];
    {
        const u16* qp_ = Qb + (size_t)bh * 65536 + (size_t)(n0 + wq0 + l15) * 64;
        qf[0] = *(const s16x8*)(qp_ + lg * 8);
        qf[1] = *(const s16x8*)(qp_ + 32 + lg * 8);
    }
    float qx[4], qy[4], qz[4];
    #pragma unroll
    for (int r = 0; r < 4; ++r) {
        const int qn = n0 + wq0 + lg * 4 + r;
        qx[r] = cmx[qn]; qy[r] = cmy[qn]; qz[r] = cmz[qn];
    }

    float m_run[4], l_run[4];
    f32x4 o_acc[4];
    const f32x4 zero = {0.f, 0.f, 0.f, 0.f};
    #pragma unroll
    for (int r = 0; r < 4; ++r) { m_run[r] = NEG_INF; l_run[r] = 0.f; }
    #pragma unroll
    for (int kf = 0; kf < 4; ++kf) o_acc[kf] = zero;

    const u16* Kbh = Kb + (size_t)bh * 65536;
    const u16* Vbh = Vtb + (size_t)bh * 65536;

    for (int mt = 0; mt < 16; ++mt) {
        const int m0 = mt * 64;

        // S = Q K^T, K fragments straight from global (L2-resident)
        f32x4 s[4];
        #pragma unroll
        for (int mf = 0; mf < 4; ++mf) {
            const u16* kp_ = Kbh + (size_t)(m0 + mf * 16 + l15) * 64;
            s16x8 kf0 = *(const s16x8*)(kp_ + lg * 8);
            s16x8 kf1 = *(const s16x8*)(kp_ + 32 + lg * 8);
            f32x4 a = zero;
            a = MFMA(qf[0], kf0, a);
            a = MFMA(qf[1], kf1, a);
            s[mf] = a;
        }

        // V fragments issued early (independent of softmax) to hide latency
        s16x8 vfr[2][4];
        #pragma unroll
        for (int ms = 0; ms < 2; ++ms)
            #pragma unroll
            for (int kf = 0; kf < 4; ++kf)
                vfr[ms][kf] = *(const s16x8*)(Vbh + (size_t)(kf * 16 + l15) * 1024
                                              + m0 + ms * 32 + lg * 8);

        // masked logits + online softmax (fp32 coords, direct differences)
        float p[4][4];
        float tmax[4] = {NEG_INF, NEG_INF, NEG_INF, NEG_INF};
        #pragma unroll
        for (int mf = 0; mf < 4; ++mf) {
            const int mloc = m0 + mf * 16 + l15;
            const float mx = cmx[mloc], my = cmy[mloc], mz = cmz[mloc];
            #pragma unroll
            for (int r = 0; r < 4; ++r) {
                const float dx = qx[r] - mx, dy = qy[r] - my, dz = qz[r] - mz;
                const float d2 = fmaf(dx, dx, fmaf(dy, dy, dz * dz));
                const bool valid = (d2 >= lo) && (d2 <= hi);
                const float lgt = fmaf(s[mf][r], 0.125f, d2 * g);
                const float v = valid ? lgt : NEG_INF;
                p[mf][r] = v;
                tmax[r] = fmaxf(tmax[r], v);
            }
        }
        #pragma unroll
        for (int r = 0; r < 4; ++r) {
            float v = tmax[r];
            v = fmaxf(v, __shfl_xor(v, 1));
            v = fmaxf(v, __shfl_xor(v, 2));
            v = fmaxf(v, __shfl_xor(v, 4));
            v = fmaxf(v, __shfl_xor(v, 8));
            const float mnew = fmaxf(m_run[r], v);
            const float scale = (mnew == NEG_INF) ? 1.f : __expf(m_run[r] - mnew);
            m_run[r] = mnew;
            float rs = 0.f;
            #pragma unroll
            for (int mf = 0; mf < 4; ++mf) {
                const float pv = (p[mf][r] == NEG_INF) ? 0.f : __expf(p[mf][r] - mnew);
                p[mf][r] = pv;
                rs += pv;
            }
            rs += __shfl_xor(rs, 1); rs += __shfl_xor(rs, 2);
            rs += __shfl_xor(rs, 4); rs += __shfl_xor(rs, 8);
            l_run[r] = l_run[r] * scale + rs;
            #pragma unroll
            for (int kf = 0; kf < 4; ++kf) o_acc[kf][r] *= scale;
        }

        // P -> wave-private LDS (no barrier: same-wave dependency only)
        #pragma unroll
        for (int mf = 0; mf < 4; ++mf)
            #pragma unroll
            for (int r = 0; r < 4; ++r)
                Ps[wid][lg * 4 + r][mf * 16 + l15] = f2b(p[mf][r]);

        // O += P V
        #pragma unroll
        for (int ms = 0; ms < 2; ++ms) {
            s16x8 pa = *(const s16x8*)&Ps[wid][l15][ms * 32 + lg * 8];
            #pragma unroll
            for (int kf = 0; kf < 4; ++kf)
                o_acc[kf] = MFMA(pa, vfr[ms][kf], o_acc[kf]);
        }
    }

    #pragma unroll
    for (int kf = 0; kf < 4; ++kf) {
        #pragma unroll
        for (int r = 0; r < 4; ++r) {
            const int n = n0 + wq0 + lg * 4 + r;
            const float invl = (l_run[r] > 0.f) ? 1.f / l_run[r] : 0.f;
            Ob[((size_t)b * 1024 + n) * 512 + h * 64 + kf * 16 + l15] = f2b(o_acc[kf][r] * invl);
        }
    }
}

// ============================ fused add(+partials)(+colbias) + LayerNorm =====
template<int NSRC, bool CB, bool WB16>
__global__ __launch_bounds__(256) void add_ln_kernel(
    const float* __restrict__ a, const float* __restrict__ b0, const float* __restrict__ b1,
    const float* __restrict__ cb, const float* __restrict__ g, const float* __restrict__ bt,
    float* __restrict__ out, u16* __restrict__ outb)
{
    const int lane = threadIdx.x & 63;
    const int row = blockIdx.x * 4 + (threadIdx.x >> 6);
    const size_t base = (size_t)row * 512 + lane * 8;

    float v[8];
    {
        float4 a0 = *(const float4*)(a + base);
        float4 a1 = *(const float4*)(a + base + 4);
        float4 p0 = *(const float4*)(b0 + base);
        float4 p1 = *(const float4*)(b0 + base + 4);
        v[0]=a0.x+p0.x; v[1]=a0.y+p0.y; v[2]=a0.z+p0.z; v[3]=a0.w+p0.w;
        v[4]=a1.x+p1.x; v[5]=a1.y+p1.y; v[6]=a1.z+p1.z; v[7]=a1.w+p1.w;
        if (NSRC == 3) {
            float4 q0 = *(const float4*)(b1 + base);
            float4 q1 = *(const float4*)(b1 + base + 4);
            v[0]+=q0.x; v[1]+=q0.y; v[2]+=q0.z; v[3]+=q0.w;
            v[4]+=q1.x; v[5]+=q1.y; v[6]+=q1.z; v[7]+=q1.w;
        }
        if (CB) {
            float4 c0 = *(const float4*)(cb + lane * 8);
            float4 c1 = *(const float4*)(cb + lane * 8 + 4);
            v[0]+=c0.x; v[1]+=c0.y; v[2]+=c0.z; v[3]+=c0.w;
            v[4]+=c1.x; v[5]+=c1.y; v[6]+=c1.z; v[7]+=c1.w;
        }
    }
    float s = 0.f;
    #pragma unroll
    for (int k = 0; k < 8; ++k) s += v[k];
    #pragma unroll
    for (int m = 1; m <= 32; m <<= 1) s += __shfl_xor(s, m);
    const float mean = s * (1.0f / 512.0f);

    float vs = 0.f;
    #pragma unroll
    for (int k = 0; k < 8; ++k) { const float d = v[k] - mean; vs += d * d; }
    #pragma unroll
    for (int m = 1; m <= 32; m <<= 1) vs += __shfl_xor(vs, m);
    const float rstd = rsqrtf(vs * (1.0f / 512.0f) + 1e-5f);

    float4 g0 = *(const float4*)(g + lane * 8);
    float4 g1 = *(const float4*)(g + lane * 8 + 4);
    float4 t0 = *(const float4*)(bt + lane * 8);
    float4 t1 = *(const float4*)(bt + lane * 8 + 4);
    float gg[8] = {g0.x,g0.y,g0.z,g0.w,g1.x,g1.y,g1.z,g1.w};
    float tb[8] = {t0.x,t0.y,t0.z,t0.w,t1.x,t1.y,t1.z,t1.w};

    float o[8];
    #pragma unroll
    for (int k = 0; k < 8; ++k) o[k] = (v[k] - mean) * rstd * gg[k] + tb[k];
    float4 w0; w0.x=o[0]; w0.y=o[1]; w0.z=o[2]; w0.w=o[3];
    float4 w1; w1.x=o[4]; w1.y=o[5]; w1.z=o[6]; w1.w=o[7];
    *(float4*)(out + base) = w0;
    *(float4*)(out + base + 4) = w1;
    if (WB16) {
        s16x8 q;
        #pragma unroll
        for (int k = 0; k < 8; ++k) q[k] = (short)f2b(o[k]);
        *(s16x8*)(outb + base) = q;
    }
}

// ============================ launch =========================================
extern "C" void kernel_launch(void* const* d_in, const int* in_sizes, int n_in,
                              void* d_out, int out_size, void* d_ws, size_t ws_size,
                              hipStream_t stream)
{
    const float* x      = (const float*)d_in[0];
    const float* coords = (const float*)d_in[1];
    const float* qp     = (const float*)d_in[2];
    const float* kp     = (const float*)d_in[3];
    const float* vp     = (const float*)d_in[4];
    const float* qbias  = (const float*)d_in[5];
    const float* kbias  = (const float*)d_in[6];
    const float* vbias  = (const float*)d_in[7];
    const float* w_out  = (const float*)d_in[8];
    const float* ln1g   = (const float*)d_in[9];
    const float* ln1b   = (const float*)d_in[10];
    const float* w1     = (const float*)d_in[11];
    const float* b1     = (const float*)d_in[12];
    const float* w2     = (const float*)d_in[13];
    const float* b2     = (const float*)d_in[14];
    const float* ln2g   = (const float*)d_in[15];
    const float* ln2b   = (const float*)d_in[16];
    float* out = (float*)d_out;

    char* W = (char*)d_ws;
    u16*  xb     = (u16*)(W + 0);                    //  4 MiB
    u16*  Bqkv   = (u16*)(W + 4194304);              //  1.5 MiB
    u16*  w_outp = (u16*)(W + 5767168);              //  0.5 MiB
    u16*  w1b    = (u16*)(W + 6291456);              //  1 MiB
    u16*  w2b    = (u16*)(W + 7340032);              //  1 MiB
    u16*  Qb     = (u16*)(W + 8388608);              //  4 MiB
    u16*  Kb     = (u16*)(W + 12582912);             //  4 MiB
    u16*  Vtb    = (u16*)(W + 16777216);             //  4 MiB
    u16*  Ob     = (u16*)(W + 20971520);             //  4 MiB
    float* X1    = (float*)(W + 25165824);           //  8 MiB
    u16*  Hb     = (u16*)(W + 33554432);             //  8 MiB
    float* P0    = (float*)(W + 41943040);           // 16 MiB (2 split-K partials)
    float* P1    = P0 + 2097152;
    u16*  X1b    = Qb;                               // reuse (Q dead after attn)

    AttnParams prm;
    for (int h = 0; h < 8; ++h) {
        const double sg = 1.0 + 5.0 * (pow(20.0, (double)h / 7.0) - 1.0) / 19.0;
        const double s2 = sg * sg;
        prm.g[h]  = (float)(-1.0 / s2);
        prm.lo[h] = (float)(2.0 * s2 * log(100.0 / 99.0));
        prm.hi[h] = (float)(2.0 * s2 * log(100.0));
    }

    prep_kernel<<<1024, 256, 0, stream>>>(x, qp, kp, vp, w_out, w1, w2,
                                          xb, Bqkv, w_outp, w1b, w2b);
    gemm_qkv_kernel<<<dim3(64, 12), 256, 0, stream>>>(xb, Bqkv, qbias, kbias, vbias,
                                                      Qb, Kb, Vtb);
    attn_kernel<<<512, 256, 0, stream>>>(Qb, Kb, Vtb, coords, Ob, prm);
    // out-proj: split-K x2 partials -> P0/P1
    gemm_kernel<0><<<dim3(64, 4, 2), 256, 0, stream>>>(Ob, w_outp, nullptr, P0, nullptr,
                                                       512, 512, 4, 2097152);
    add_ln_kernel<3, false, true><<<1024, 256, 0, stream>>>(x, P0, P1, nullptr,
                                                            ln1g, ln1b, X1, X1b);
    gemm_kernel<2><<<dim3(64, 8), 256, 0, stream>>>(X1b, w1b, b1, nullptr, Hb,
                                                    1024, 512, 8, 0);
    // ffn2: split-K x2 partials (b2 folded into LN2)
    gemm_kernel<0><<<dim3(64, 4, 2), 256, 0, stream>>>(Hb, w2b, nullptr, P0, nullptr,
                                                       512, 1024, 8, 2097152);
    add_ln_kernel<3, true, false><<<1024, 256, 0, stream>>>(X1, P0, P1, b2,
                                                            ln2g, ln2b, out, nullptr);
}